// Round 7
// baseline (216.781 us; speedup 1.0000x reference)
//
#include <hip/hip_runtime.h>

// CTC batch cost, forward algorithm. B=512, T=512, C=128 (blank=127), L=64, S=129.
//
// R7: same linear-domain recurrence as R6 (validated), but the memory path is
// restructured: R6's per-lane GLOBAL gathers (64-address loads spanning ~8
// cache lines each, 2/slot, 32 in flight) oversubscribed the CU's
// miss-tracking and throttled issue (~267 cyc/step). Now:
//   - rows fetched COALESCED+WIDE: 16-row chunks (8 KB) via 8x
//     global_load_dwordx4 (1 KB/instr) into a 3-chunk register pipeline
//     (~96 VGPRs, 2-chunk = ~1500 cyc latency cover),
//   - staged to a 2-chunk LDS ring (16 KB) via 8x ds_write_b128,
//   - per slot the wave does 2 ds_read_b32 (p[lab] intra-row gather +
//     p[blank] broadcast) with a 4-slot register ring for lgkm cover.
// SINGLE wave, ZERO barriers (same-wave DS is in-order: write->read safe),
// so there is no vmcnt-drain-at-barrier problem.
// Outer chunk loop steps by 3 chunks so reg-set indices are compile-time.
// lane i owns states 2i+1 (aA) and 2i+2 (aB); state 0 = uniform scalar aZ.
// Underflow: uniform 2^k rescale every 8 slots (measure at j&7==3, apply
// stale at j&7==7), exponent count folded in with one log2 at the end.

constexpr float EPSF = 1e-7f;
constexpr float LN2F = 0.6931471805599453f;

template<int CTRL>
__device__ __forceinline__ float dpp_mov(float x) {
    return __int_as_float(__builtin_amdgcn_update_dpp(
        0, __float_as_int(x), CTRL, 0xF, 0xF, true));   // bound_ctrl: 0-fill
}

__global__ __launch_bounds__(64)
void ctc_fwd(const int* __restrict__ y_true,
             const float* __restrict__ y_pred,
             float* __restrict__ out)
{
    const int b    = blockIdx.x;
    const int lane = threadIdx.x;   // 0..63

    // float4 view: row r = 32 float4; chunk k (16 rows) = 512 float4
    const float4* __restrict__ gsrc =
        (const float4*)(y_pred + (size_t)b * 512 * 128);

    __shared__ __align__(16) float lds[2 * 2048];   // 2 chunk slots x 16r x 128c

    const int   lab   = y_true[b * 64 + lane];      // label of state 2*lane+1
    const int   labp  = __shfl_up(lab, 1, 64);      // prologue-only
    const float skipf = (lane > 0 && lab != labp) ? 1.0f : 0.0f;
    const bool  l0    = (lane == 0);

    float4 regs[3][8];              // 3 chunks in flight, 8 x 16B/lane each

    auto issueLoads = [&](int chunk, int set) {     // chunk*8KB -> regs[set]
        #pragma unroll
        for (int k = 0; k < 8; ++k)
            regs[set][k] = gsrc[chunk * 512 + k * 64 + lane];
    };
    auto writeChunk = [&](int chunk, int set) {     // regs[set] -> LDS slot
        float* dst = &lds[(chunk & 1) * 2048];
        #pragma unroll
        for (int k = 0; k < 8; ++k)
            *(float4*)(dst + k * 256 + lane * 4) = regs[set][k];
    };

    float plr[4], pbr[4];           // ds_read ring, 4 slots of lgkm cover
    auto issueRead = [&](int t) {   // t&3 must fold to a constant at call site
        int tn = t > 511 ? 511 : t;
        const float* rb = &lds[((tn >> 4) & 1) * 2048 + (tn & 15) * 128];
        plr[t & 3] = rb[lab];
        pbr[t & 3] = rb[127];
    };

    float aZ, aA, aB;               // alpha[0] (uniform), alpha[2i+1], alpha[2i+2]
    int   shift = 0;                // sum of applied log2 scale exponents
    float red   = 0.0f;             // staged wave-max

    auto consume = [&](int t, int j) {
        float pl = plr[j & 3] + EPSF;
        float pb = pbr[j & 3] + EPSF;
        float upA = dpp_mov<0x138>(aA);    // alpha[2i-1]; lane0 -> 0 (correct)
        float upB = dpp_mov<0x138>(aB);    // alpha[2i]
        upB = l0 ? aZ : upB;               // lane0's s-1 is state 0
        float ts = fmaf(skipf, upA, aA + upB);
        float nA = pl * ts;
        float nB = pb * (aB + aA);
        aZ *= pb;
        aA = nA; aB = nB;
        if ((j & 7) == 3) {                // measure wave-max (applied at +4)
            float r = fmaxf(fmaxf(aA, aB), aZ);
            r = fmaxf(r, dpp_mov<0x111>(r));   // row_shr:1
            r = fmaxf(r, dpp_mov<0x112>(r));   // row_shr:2
            r = fmaxf(r, dpp_mov<0x114>(r));   // row_shr:4
            r = fmaxf(r, dpp_mov<0x118>(r));   // row_shr:8
            r = fmaxf(r, dpp_mov<0x142>(r));   // row_bcast:15
            r = fmaxf(r, dpp_mov<0x143>(r));   // row_bcast:31
            red = r;
        }
        if ((j & 7) == 7) {                // apply uniform 2^k rescale
            int mb = __builtin_amdgcn_readlane(__float_as_int(red), 63);
            int e  = (mb >> 23) & 0xff;
            int f  = 314 - e;              // target: max -> ~2^60
            f = f < 1 ? 1 : (f > 254 ? 254 : f);
            float scale = __int_as_float(f << 23);
            shift += f - 127;
            aA *= scale; aB *= scale; aZ *= scale;
        }
        issueRead(t + 4);
    };

    // ---- prologue: chunks 0,1,2 in flight; chunk 0 staged; reads primed ----
    issueLoads(0, 0); issueLoads(1, 1); issueLoads(2, 2);
    writeChunk(0, 0);
    issueRead(0); issueRead(1); issueRead(2); issueRead(3);
    {
        float pb0 = pbr[0] + EPSF;
        float pl0 = plr[0] + EPSF;
        aZ = pb0;                   // state 0
        aA = l0 ? pl0 : 0.0f;       // state 1 (lane 0 only)
        aB = 0.0f;                  // states >= 2 unreachable at t=0
    }
    issueRead(4);                   // slot 0 consumed above; refill its ring slot

    // ---- chunk 0: consume t = 1..15 ----
    issueLoads(3, 0);               // set 0 free (chunk 0 already staged)
    writeChunk(1, 1);
    #pragma unroll
    for (int j = 1; j < 16; ++j) consume(j, j);

    // ---- chunks 1..30, stepped by 3 so set indices are compile-time ----
    for (int cb = 1; cb <= 28; cb += 3) {
        // c = cb (== 1 mod 3): load chunk c+3 -> set 1, write c+1 from set 2
        {
            int c = cb;
            if (c + 3 < 32) issueLoads(c + 3, 1);
            writeChunk(c + 1, 2);
            #pragma unroll
            for (int j = 0; j < 16; ++j) consume(16 * c + j, j);
        }
        // c = cb+1 (== 2 mod 3): load c+3 -> set 2, write c+1 from set 0
        {
            int c = cb + 1;
            if (c + 3 < 32) issueLoads(c + 3, 2);
            writeChunk(c + 1, 0);
            #pragma unroll
            for (int j = 0; j < 16; ++j) consume(16 * c + j, j);
        }
        // c = cb+2 (== 0 mod 3): load c+3 -> set 0, write c+1 from set 1
        {
            int c = cb + 2;
            if (c + 3 < 32) issueLoads(c + 3, 0);
            writeChunk(c + 1, 1);
            #pragma unroll
            for (int j = 0; j < 16; ++j) consume(16 * c + j, j);
        }
    }

    // ---- tail: chunk 31 (already staged by c=30's writeChunk) ----
    #pragma unroll
    for (int j = 0; j < 16; ++j) consume(16 * 31 + j, j);

    // ll = log(alpha[127] + alpha[128]) - shift*ln2; both on lane 63
    float s   = aA + aB;
    float ll2 = __builtin_amdgcn_logf(s);          // log2
    if (lane == 63) out[b] = ((float)shift - ll2) * LN2F;
}

extern "C" void kernel_launch(void* const* d_in, const int* in_sizes, int n_in,
                              void* d_out, int out_size, void* d_ws, size_t ws_size,
                              hipStream_t stream)
{
    const int*   y_true = (const int*)d_in[0];    // [B, L] int32
    const float* y_pred = (const float*)d_in[1];  // [B, T, C] float32
    float*       out    = (float*)d_out;          // [B, 1] float32

    const int B = out_size;   // 512
    ctc_fwd<<<dim3(B), dim3(64), 0, stream>>>(y_true, y_pred, out);
}

// Round 8
// 191.986 us; speedup vs baseline: 1.1292x; 1.1292x over previous
//
#include <hip/hip_runtime.h>

// CTC batch cost, forward algorithm. B=512, T=512, C=128 (blank=127), L=64, S=129.
//
// R8: R7's coalesced-fetch idea, but with the register pipeline replaced by
// DIRECT global->LDS DMA (__builtin_amdgcn_global_load_lds, 16 B/lane), which
// has ZERO VGPR cost. R7's regs[3][8] (384 VGPRs) spilled to scratch
// (WRITE_SIZE 107 MB, VGPR_Count 72) and serialized the pipeline.
//   - 8-slot LDS ring, 1 slot = 1 chunk = 16 rows x 128 ch = 8 KB (64 KB LDS).
//   - chunk c+4 issued while consuming chunk c (48 slots ~ 1800 cyc >> 900-cyc
//     HBM latency); slot (c+4)&7 is disjoint from the slots being read.
//   - explicit s_waitcnt vmcnt(16) before chunk c guarantees chunks <= c+1
//     landed (loads complete in order; 8 loads/chunk).
//   - consumption: 2 ds_read_b32 per slot (p[lab] intra-row gather + p[blank]
//     broadcast), 4-slot register ring for lgkm cover. Single wave, 0 barriers.
// Recurrence (linear/probability domain, validated in R6): pure add/fma/mul,
// DPP wave_shr:1 neighbors, uniform 2^k rescale every 8 slots, one log2 at end.
// lane i owns states 2i+1 (aA) and 2i+2 (aB); state 0 = uniform scalar aZ.

constexpr float EPSF = 1e-7f;
constexpr float LN2F = 0.6931471805599453f;

template<int CTRL>
__device__ __forceinline__ float dpp_mov(float x) {
    return __int_as_float(__builtin_amdgcn_update_dpp(
        0, __float_as_int(x), CTRL, 0xF, 0xF, true));   // bound_ctrl: 0-fill
}

// wait until at most N vector-memory ops outstanding (ignore exp/lgkm)
#define WAITVM(n) __builtin_amdgcn_s_waitcnt( ((n) & 0xF) | ((((n) >> 4) & 0x3) << 14) \
                                            | (0x7 << 4) | (0xF << 8) )

__global__ __launch_bounds__(64)
void ctc_fwd(const int* __restrict__ y_true,
             const float* __restrict__ y_pred,
             float* __restrict__ out)
{
    const int b    = blockIdx.x;
    const int lane = threadIdx.x;   // 0..63

    __shared__ __align__(16) float lds[8 * 2048];   // 8 slots x 16r x 128c = 64 KB

    // float4 view: row = 32 float4, chunk (16 rows) = 512 float4
    const float4* __restrict__ gsrc =
        (const float4*)(y_pred + (size_t)b * 512 * 128);

    const int   lab   = y_true[b * 64 + lane];      // label of state 2*lane+1
    const int   labp  = __shfl_up(lab, 1, 64);      // prologue-only
    const float skipf = (lane > 0 && lab != labp) ? 1.0f : 0.0f;
    const bool  l0    = (lane == 0);

    // DMA one 16-row chunk into LDS slot c&7: 8x (64 lanes x 16 B) = 8 KB.
    // HW places lane i's 16 B at ldsbase + i*16 -> row-major contiguous.
    auto issueChunk = [&](int c) {
        const float4* g = gsrc + c * 512 + lane;
        #pragma unroll
        for (int k = 0; k < 8; ++k)
            __builtin_amdgcn_global_load_lds(
                (const __attribute__((address_space(1))) void*)(g + k * 64),
                (__attribute__((address_space(3))) void*)&lds[(c & 7) * 2048 + k * 256],
                16, 0, 0);
    };

    float plr[4], pbr[4];           // ds_read ring, 4 slots of lgkm cover
    auto issueRead = [&](int t, int q) {   // q = ring slot (compile-time)
        int tn = t > 511 ? 511 : t;
        const float* rb = &lds[((tn >> 4) & 7) * 2048 + (tn & 15) * 128];
        plr[q] = rb[lab];
        pbr[q] = rb[127];
    };

    float aZ, aA, aB;               // alpha[0] (uniform), alpha[2i+1], alpha[2i+2]
    int   shift = 0;                // sum of applied log2 scale exponents
    float red   = 0.0f;             // staged wave-max

    auto consume = [&](int t, int j) {
        float pl = plr[j & 3] + EPSF;
        float pb = pbr[j & 3] + EPSF;
        float upA = dpp_mov<0x138>(aA);    // alpha[2i-1]; lane0 -> 0 (correct)
        float upB = dpp_mov<0x138>(aB);    // alpha[2i]
        upB = l0 ? aZ : upB;               // lane0's s-1 is state 0
        float ts = fmaf(skipf, upA, aA + upB);
        float nA = pl * ts;
        float nB = pb * (aB + aA);
        aZ *= pb;
        aA = nA; aB = nB;
        if ((j & 7) == 3) {                // measure wave-max (applied at +4)
            float r = fmaxf(fmaxf(aA, aB), aZ);
            r = fmaxf(r, dpp_mov<0x111>(r));   // row_shr:1
            r = fmaxf(r, dpp_mov<0x112>(r));   // row_shr:2
            r = fmaxf(r, dpp_mov<0x114>(r));   // row_shr:4
            r = fmaxf(r, dpp_mov<0x118>(r));   // row_shr:8
            r = fmaxf(r, dpp_mov<0x142>(r));   // row_bcast:15
            r = fmaxf(r, dpp_mov<0x143>(r));   // row_bcast:31
            red = r;
        }
        if ((j & 7) == 7) {                // apply uniform 2^k rescale
            int mb = __builtin_amdgcn_readlane(__float_as_int(red), 63);
            int e  = (mb >> 23) & 0xff;
            int f  = 314 - e;              // target: max -> ~2^60
            f = f < 1 ? 1 : (f > 254 ? 254 : f);
            float scale = __int_as_float(f << 23);
            shift += f - 127;
            aA *= scale; aB *= scale; aZ *= scale;
        }
        issueRead(t + 4, j & 3);           // refill the slot just consumed
    };

    // ---- prologue: chunks 0..3 in flight; wait chunks 0,1; prime reads ----
    issueChunk(0); issueChunk(1); issueChunk(2); issueChunk(3);
    WAITVM(16);                     // chunks 0,1 landed (16 = chunks 2,3 left)
    issueRead(0, 0); issueRead(1, 1); issueRead(2, 2); issueRead(3, 3);
    {
        float pb0 = pbr[0] + EPSF;
        float pl0 = plr[0] + EPSF;
        aZ = pb0;                   // state 0
        aA = l0 ? pl0 : 0.0f;       // state 1 (lane 0 only)
        aB = 0.0f;                  // states >= 2 unreachable at t=0
    }
    issueRead(4, 0);                // slot 0 consumed by init; refill

    // ---- chunk 0: consume t = 1..15 ----
    issueChunk(4);
    #pragma unroll
    for (int j = 1; j < 16; ++j) consume(j, j);

    // ---- chunks 1..28: wait (c+1 landed), issue c+4, consume 16 ----
    for (int c = 1; c <= 28; ++c) {
        WAITVM(16);                 // outstanding <= chunks c+2,c+3
        if (c <= 27) issueChunk(c + 4);
        #pragma unroll
        for (int j = 0; j < 16; ++j) consume(16 * c + j, j);
    }
    // ---- chunk 29: need chunk 30 landed (only 31 may remain) ----
    WAITVM(8);
    #pragma unroll
    for (int j = 0; j < 16; ++j) consume(16 * 29 + j, j);
    // ---- chunk 30: need chunk 31 landed ----
    WAITVM(0);
    #pragma unroll
    for (int j = 0; j < 16; ++j) consume(16 * 30 + j, j);
    // ---- chunk 31: everything resident ----
    #pragma unroll
    for (int j = 0; j < 16; ++j) consume(16 * 31 + j, j);

    // ll = log(alpha[127] + alpha[128]) - shift*ln2; both on lane 63
    float s   = aA + aB;
    float ll2 = __builtin_amdgcn_logf(s);          // log2
    if (lane == 63) out[b] = ((float)shift - ll2) * LN2F;
}

extern "C" void kernel_launch(void* const* d_in, const int* in_sizes, int n_in,
                              void* d_out, int out_size, void* d_ws, size_t ws_size,
                              hipStream_t stream)
{
    const int*   y_true = (const int*)d_in[0];    // [B, L] int32
    const float* y_pred = (const float*)d_in[1];  // [B, T, C] float32
    float*       out    = (float*)d_out;          // [B, 1] float32

    const int B = out_size;   // 512
    ctc_fwd<<<dim3(B), dim3(64), 0, stream>>>(y_true, y_pred, out);
}